// Round 10
// baseline (1491.311 us; speedup 1.0000x reference)
//
#include <hip/hip_runtime.h>
#include <stdint.h>

#define B_    256
#define T_    77
#define E_    1280
#define H_    20
#define T2_   154
#define MTOK  19712   // B_*T_
#define MTOK2 39424   // B_*T2_

#define BM2 256
#define BN2 128
#define BK2 64

typedef float f32x4 __attribute__((ext_vector_type(4)));
typedef short bf16x8 __attribute__((ext_vector_type(8)));

__device__ inline float bf2f(short s) {
    return __uint_as_float(((unsigned)(unsigned short)s) << 16);
}
__device__ inline short f2bf(float f) {
    unsigned u = __float_as_uint(f);
    u += 0x7fff + ((u >> 16) & 1);   // RNE
    return (short)(u >> 16);
}
__device__ inline float gelu_tanh(float x) {   // jax.nn.gelu approximate=True
    float x3 = x * x * x;
    return 0.5f * x * (1.0f + tanhf(0.7978845608028654f * (x + 0.044715f * x3)));
}

// ---------------- fp32 -> bf16 cast ----------------
__global__ void cast_f32_bf16(const float* __restrict__ in, short* __restrict__ out, int n4) {
    int i = blockIdx.x * blockDim.x + threadIdx.x;
    int stride = gridDim.x * blockDim.x;
    for (; i < n4; i += stride) {
        float4 v = reinterpret_cast<const float4*>(in)[i];
        short4 o;
        o.x = f2bf(v.x); o.y = f2bf(v.y); o.z = f2bf(v.z); o.w = f2bf(v.w);
        reinterpret_cast<short4*>(out)[i] = o;
    }
}

// ---------------- pad token-mix weight: fp32 (rows x cols) -> bf16 [80][KP], zero pad ----
__global__ void pad_weight(const float* __restrict__ W, short* __restrict__ Wp,
                           int rows, int cols, int KP) {
    int i = blockIdx.x * 256 + threadIdx.x;
    if (i >= 80 * KP) return;
    int t = i / KP, s = i - t * KP;
    Wp[i] = (t < rows && s < cols) ? f2bf(W[t * cols + s]) : (short)0;
}

// ---------------- bf16 GEMM: C[M,N] = A[M,K] @ W[N,K]^T (+epilogue) -------------
// R10 structure: 256x128 tile, BK=64, 8 waves (2Mx4N, each 128x32 out), LDS dbuf
// 96 KB, depth-1 prefetch with COUNTED vmcnt(6) + raw s_barrier (loads for tile
// kt+1 stay in flight across the barrier while tile kt computes; never drain to
// 0 in the loop). T1 XCD swizzle (R8) + T2 both-sides LDS XOR swizzle (R9,
// conflicts 4.7e7 -> 0) + T5 setprio around the MFMA cluster.
// Safety: tile kt+1 -> buf[(kt+1)&1], last read in iter kt-1, separated from
// this issue by iter kt-1's end barrier; vmcnt(6)+barrier A ensures ALL waves'
// tile-kt loads landed before any ds_read of buf[kt&1].
// EPI: 0 = +bias -> bf16 ; 1 = (+bias)*scale -> bf16 ; 2 = gelu(+bias) -> bf16 ;
//      3 = +bias -> fp32
template<int EPI>
__global__ __launch_bounds__(512, 2)
void gemm_bt(const short* __restrict__ A, const short* __restrict__ W,
             const float* __restrict__ bias, void* __restrict__ Cout,
             int K, float scale) {
    const int N = E_;
    const int NBN = E_ / BN2;            // 10 N-tiles
    __shared__ short Als[2][BM2 * BK2];  // 2 x 32 KB
    __shared__ short Bls[2][BN2 * BK2];  // 2 x 16 KB
    const int tid  = threadIdx.x;
    const int wave = tid >> 6, lane = tid & 63;

    // bijective XCD swizzle (m204): XCD x = p%8 gets a contiguous logical chunk
    const int nwg = gridDim.x;
    const int qq = nwg >> 3, rr = nwg & 7;
    const int x = blockIdx.x & 7, ii = blockIdx.x >> 3;
    const int L = (x < rr ? x * (qq + 1) : rr * (qq + 1) + (x - rr) * qq) + ii;
    const int bm = L / NBN, bn = L % NBN;

    const int wr = wave >> 2, wc = wave & 3;   // wave tile: rows wr*128, cols wc*32

    f32x4 acc[8][2] = {};

    const long arow0 = (long)bm * BM2;
    const long brow0 = (long)bn * BN2;
    const int trow = tid >> 3;                           // 0..63: staging row within round
    const int tcol = (((tid & 7) ^ ((tid >> 3) & 7))) * 8;  // pre-swizzled source col
    const int swz  = (lane & 7) << 3;                    // read-side XOR (shorts)
    const int NT = K / BK2;

    auto ISSUE = [&](int kt) {
        const int b = kt & 1;
        const short* ab = A + arow0 * K + kt * BK2;
#pragma unroll
        for (int r = 0; r < 4; ++r) {                    // A: 256 rows, 4 rounds
            const short* ga = ab + (long)(r * 64 + trow) * K + tcol;
            __builtin_amdgcn_global_load_lds(
                (const __attribute__((address_space(1))) unsigned int*)ga,
                (__attribute__((address_space(3))) unsigned int*)&Als[b][r * 4096 + wave * 512],
                16, 0, 0);
        }
        const short* bb = W + brow0 * K + kt * BK2;
#pragma unroll
        for (int r = 0; r < 2; ++r) {                    // B: 128 rows, 2 rounds
            const short* gb = bb + (long)(r * 64 + trow) * K + tcol;
            __builtin_amdgcn_global_load_lds(
                (const __attribute__((address_space(1))) unsigned int*)gb,
                (__attribute__((address_space(3))) unsigned int*)&Bls[b][r * 4096 + wave * 512],
                16, 0, 0);
        }
    };

    ISSUE(0);
    for (int kt = 0; kt < NT; ++kt) {
        if (kt + 1 < NT) {
            ISSUE(kt + 1);
            asm volatile("s_waitcnt vmcnt(6)" ::: "memory");   // tile kt done; kt+1 in flight
        } else {
            asm volatile("s_waitcnt vmcnt(0)" ::: "memory");   // last tile: full drain
        }
        __builtin_amdgcn_sched_barrier(0);
        __builtin_amdgcn_s_barrier();                          // all waves' kt loads landed

        const short* Ab = Als[kt & 1];
        const short* Bb = Bls[kt & 1];
#pragma unroll
        for (int kk = 0; kk < 2; ++kk) {
            bf16x8 af[8], bfr[2];
#pragma unroll
            for (int mi = 0; mi < 8; ++mi)
                af[mi] = *reinterpret_cast<const bf16x8*>(
                    &Ab[((wr * 128 + mi * 16 + (lane & 15)) * 64 + kk * 32 + (lane >> 4) * 8) ^ swz]);
#pragma unroll
            for (int nj = 0; nj < 2; ++nj)
                bfr[nj] = *reinterpret_cast<const bf16x8*>(
                    &Bb[((wc * 32 + nj * 16 + (lane & 15)) * 64 + kk * 32 + (lane >> 4) * 8) ^ swz]);
            __builtin_amdgcn_s_setprio(1);
#pragma unroll
            for (int mi = 0; mi < 8; ++mi)
#pragma unroll
                for (int nj = 0; nj < 2; ++nj)
                    acc[mi][nj] = __builtin_amdgcn_mfma_f32_16x16x32_bf16(
                        af[mi], bfr[nj], acc[mi][nj], 0, 0, 0);
            __builtin_amdgcn_s_setprio(0);
        }
        __builtin_amdgcn_sched_barrier(0);
        __builtin_amdgcn_s_barrier();     // reads of buf[kt&1] done before next overwrite-issue
    }

    // epilogue: C/D layout col=lane&15, row=(lane>>4)*4+r  [m89-verified]
#pragma unroll
    for (int mi = 0; mi < 8; ++mi) {
#pragma unroll
        for (int nj = 0; nj < 2; ++nj) {
            int gcol = bn * BN2 + wc * 32 + nj * 16 + (lane & 15);
            float bv = bias[gcol];
#pragma unroll
            for (int r = 0; r < 4; ++r) {
                long grow = arow0 + wr * 128 + mi * 16 + (lane >> 4) * 4 + r;
                float v = acc[mi][nj][r] + bv;
                if (EPI == 1) v *= scale;
                if (EPI == 2) v = gelu_tanh(v);
                if (EPI == 3) ((float*)Cout)[grow * N + gcol] = v;
                else          ((short*)Cout)[grow * N + gcol] = f2bf(v);
            }
        }
    }
}

// ---------------- MFMA token mixer ----------------
template<int SIN, int KP, int PS, bool GELU, bool RESID>
__global__ void mixer_mfma(const short* __restrict__ IN, const short* __restrict__ Wp,
                           const float* __restrict__ bias, const short* __restrict__ Cat,
                           short* __restrict__ OUT) {
    __shared__ short lsT[64 * PS];
    const int e0 = blockIdx.x * 64;
    const int b  = blockIdx.y;
    const int tid = threadIdx.x, wave = tid >> 6, lane = tid & 63;

    const int eg = tid & 7;       // which 8-e group this thread handles
    const int sl = tid >> 3;      // s row, 32 per pass
    for (int sb = sl; sb < KP; sb += 32) {
        if (sb < SIN) {
            bf16x8 v = *reinterpret_cast<const bf16x8*>(
                &IN[((long)b * SIN + sb) * E_ + e0 + eg * 8]);
#pragma unroll
            for (int i = 0; i < 8; ++i)
                lsT[(eg * 8 + i) * PS + sb] = v[i];
        } else {
#pragma unroll
            for (int i = 0; i < 8; ++i)
                lsT[(eg * 8 + i) * PS + sb] = 0;
        }
    }
    __syncthreads();

    const int ebase = wave * 16;          // e-subtile owned by this wave
    f32x4 acc[5] = {};
#pragma unroll
    for (int ks = 0; ks < KP / 32; ++ks) {
        bf16x8 bfr = *reinterpret_cast<const bf16x8*>(
            &lsT[(ebase + (lane & 15)) * PS + ks * 32 + (lane >> 4) * 8]);
#pragma unroll
        for (int mt = 0; mt < 5; ++mt) {
            bf16x8 af = *reinterpret_cast<const bf16x8*>(
                &Wp[(mt * 16 + (lane & 15)) * KP + ks * 32 + (lane >> 4) * 8]);
            acc[mt] = __builtin_amdgcn_mfma_f32_16x16x32_bf16(af, bfr, acc[mt], 0, 0, 0);
        }
    }

    const int e = e0 + ebase + (lane & 15);
#pragma unroll
    for (int mt = 0; mt < 5; ++mt) {
#pragma unroll
        for (int r = 0; r < 4; ++r) {
            int t = mt * 16 + (lane >> 4) * 4 + r;
            if (t < T_) {
                float v = acc[mt][r] + bias[t];
                if (GELU) v = gelu_tanh(v);
                if (RESID) v += bf2f(Cat[((long)b * T2_ + T_ + t) * E_ + e]);
                OUT[((long)b * T_ + t) * E_ + e] = f2bf(v);
            }
        }
    }
}

// ---------------- fused MFMA attention: one WAVE per (b,h), both passes ----------------
#define ASTR 104   // LDS row stride (shorts): 16B-aligned, <=2-way banks on b128
__global__ __launch_bounds__(64, 1)
void attn_mfma(const short* __restrict__ Qm,
               const short* __restrict__ Km, const short* __restrict__ Vm,
               const short* __restrict__ KAm, const short* __restrict__ VAm,
               short* __restrict__ Cat) {
    __shared__ short pls[80 * ASTR];
    __shared__ short vt[64 * ASTR];
    const int hh = blockIdx.x;
    const int b = hh / H_, h = hh % H_;
    const int lane = threadIdx.x & 63;
    const int colbase = lane & 15, g = lane >> 4;
    const long base = ((long)b * T_) * E_ + h * 64;

    for (int pass = 0; pass < 2; ++pass) {
        const short* Kp = pass ? KAm : Km;
        const short* Vp = pass ? VAm : Vm;
        const bool causal = (pass == 0);
        const int rowoff = pass ? 0 : T_;

        // ---- zero LDS K-tails (cols >= valid range) BEFORE staging ----
        {
            int4 z = {0, 0, 0, 0};
#pragma unroll
            for (int it = 0; it < 4; ++it) {          // vt rows 0..63, cols 64..95
                int idx = it * 64 + lane;
                int row = idx >> 2, cb = idx & 3;
                *reinterpret_cast<int4*>(&vt[row * ASTR + 64 + cb * 8]) = z;
            }
#pragma unroll
            for (int it = 0; it < 3; ++it) {          // pls rows 0..79, cols 80..95
                int idx = it * 64 + lane;
                if (idx < 160) {
                    int row = idx >> 1, cb = idx & 1;
                    *reinterpret_cast<int4*>(&pls[row * ASTR + 80 + cb * 8]) = z;
                }
            }
        }

        // ---- stage V^T: vt[d][s] = V[s][d]; lane = s (transpose writes conflict-free) ----
        {
            const short* vb = Vp + base + (long)lane * E_;
#pragma unroll
            for (int dg = 0; dg < 8; ++dg) {
                bf16x8 v = *reinterpret_cast<const bf16x8*>(vb + dg * 8);
#pragma unroll
                for (int i = 0; i < 8; ++i) vt[(dg * 8 + i) * ASTR + lane] = v[i];
            }
            if (lane < T_ - 64) {
                const short* vb2 = Vp + base + (long)(64 + lane) * E_;
#pragma unroll
                for (int dg = 0; dg < 8; ++dg) {
                    bf16x8 v = *reinterpret_cast<const bf16x8*>(vb2 + dg * 8);
#pragma unroll
                    for (int i = 0; i < 8; ++i) vt[(dg * 8 + i) * ASTR + 64 + lane] = v[i];
                }
            }
        }

        // ---- S = Q.K^T (frags from global; A/B layout = m89-verified gemm pattern) ----
        f32x4 sacc[5][5] = {};
#pragma unroll
        for (int kk = 0; kk < 2; ++kk) {
            bf16x8 qf[5];
#pragma unroll
            for (int mi = 0; mi < 5; ++mi) {
                int t = mi * 16 + colbase; t = t > 76 ? 76 : t;
                qf[mi] = *reinterpret_cast<const bf16x8*>(
                    Qm + base + (long)t * E_ + kk * 32 + g * 8);
            }
#pragma unroll
            for (int nj = 0; nj < 5; ++nj) {
                int s = nj * 16 + colbase; s = s > 76 ? 76 : s;
                bf16x8 kf = *reinterpret_cast<const bf16x8*>(
                    Kp + base + (long)s * E_ + kk * 32 + g * 8);
#pragma unroll
                for (int mi = 0; mi < 5; ++mi)
                    sacc[mi][nj] = __builtin_amdgcn_mfma_f32_16x16x32_bf16(
                        qf[mi], kf, sacc[mi][nj], 0, 0, 0);
            }
        }

        // ---- masked softmax in C-layout; row-reduce across the 16-lane group ----
        float inv[5][4];
#pragma unroll
        for (int mi = 0; mi < 5; ++mi) {
#pragma unroll
            for (int r = 0; r < 4; ++r) {
                int t = mi * 16 + g * 4 + r;
                float mx = -3.0e38f;
#pragma unroll
                for (int nj = 0; nj < 5; ++nj) {
                    int s = nj * 16 + colbase;
                    bool ok = causal ? (s <= t) : (s < T_);
                    if (ok) mx = fmaxf(mx, sacc[mi][nj][r]);
                }
#pragma unroll
                for (int o = 1; o <= 8; o <<= 1) mx = fmaxf(mx, __shfl_xor(mx, o));
                float sum = 0.f;
#pragma unroll
                for (int nj = 0; nj < 5; ++nj) {
                    int s = nj * 16 + colbase;
                    bool ok = causal ? (s <= t) : (s < T_);
                    float pv = ok ? __expf(sacc[mi][nj][r] - mx) : 0.f;
                    sacc[mi][nj][r] = pv;
                    sum += pv;
                }
#pragma unroll
                for (int o = 1; o <= 8; o <<= 1) sum += __shfl_xor(sum, o);
                inv[mi][r] = 1.0f / sum;
            }
        }

        // ---- write unnormalized P (bf16) to LDS ----
#pragma unroll
        for (int mi = 0; mi < 5; ++mi)
#pragma unroll
            for (int nj = 0; nj < 5; ++nj)
#pragma unroll
                for (int r = 0; r < 4; ++r)
                    pls[(mi * 16 + g * 4 + r) * ASTR + nj * 16 + colbase] =
                        f2bf(sacc[mi][nj][r]);

        // ---- ctx = P.V via mfma (A = P rows, B = V^T rows; K = 96) ----
        f32x4 cacc[5][4] = {};
#pragma unroll
        for (int ks = 0; ks < 3; ++ks) {
            bf16x8 pa[5];
#pragma unroll
            for (int mi = 0; mi < 5; ++mi)
                pa[mi] = *reinterpret_cast<const bf16x8*>(
                    &pls[(mi * 16 + colbase) * ASTR + ks * 32 + g * 8]);
#pragma unroll
            for (int nd = 0; nd < 4; ++nd) {
                bf16x8 vf = *reinterpret_cast<const bf16x8*>(
                    &vt[(nd * 16 + colbase) * ASTR + ks * 32 + g * 8]);
#pragma unroll
                for (int mi = 0; mi < 5; ++mi)
                    cacc[mi][nd] = __builtin_amdgcn_mfma_f32_16x16x32_bf16(
                        pa[mi], vf, cacc[mi][nd], 0, 0, 0);
            }
        }

        // ---- epilogue: normalize by 1/rowsum, write CAT ----
#pragma unroll
        for (int mi = 0; mi < 5; ++mi)
#pragma unroll
            for (int nd = 0; nd < 4; ++nd)
#pragma unroll
                for (int r = 0; r < 4; ++r) {
                    int t = mi * 16 + g * 4 + r;
                    if (t < T_) {
                        float val = cacc[mi][nd][r] * inv[mi][r];
                        Cat[((long)b * T2_ + rowoff + t) * E_ + h * 64 + nd * 16 + colbase] =
                            f2bf(val);
                    }
                }
    }
}

extern "C" void kernel_launch(void* const* d_in, const int* in_sizes, int n_in,
                              void* d_out, int out_size, void* d_ws, size_t ws_size,
                              hipStream_t stream) {
    const float* hidden = (const float*)d_in[0];
    const float* embeds = (const float*)d_in[1];
    // d_in[2] causal_mask unused (exactly triu(-1e9) -> applied analytically)
    const float* q_w  = (const float*)d_in[3];  const float* q_b  = (const float*)d_in[4];
    const float* k_w  = (const float*)d_in[5];  const float* k_b  = (const float*)d_in[6];
    const float* v_w  = (const float*)d_in[7];  const float* v_b  = (const float*)d_in[8];
    const float* o_w  = (const float*)d_in[9];  const float* o_b  = (const float*)d_in[10];
    const float* ka_w = (const float*)d_in[11]; const float* ka_b = (const float*)d_in[12];
    const float* va_w = (const float*)d_in[13]; const float* va_b = (const float*)d_in[14];
    const float* zc1_w = (const float*)d_in[15]; const float* zc1_b = (const float*)d_in[16];
    const float* zt1_w = (const float*)d_in[17]; const float* zt1_b = (const float*)d_in[18];
    const float* zc2_w = (const float*)d_in[19]; const float* zc2_b = (const float*)d_in[20];
    const float* zt2_w = (const float*)d_in[21]; const float* zt2_b = (const float*)d_in[22];

    char* ws = (char*)d_ws;
    const size_t WSZ = (size_t)E_ * E_ * 2;      // 3,276,800 B per weight
    const size_t ASZ = (size_t)MTOK * E_ * 2;    // 50,462,720 B per activation
    short* Wq  = (short*)(ws + 0 * WSZ);
    short* Wk  = (short*)(ws + 1 * WSZ);
    short* Wv  = (short*)(ws + 2 * WSZ);
    short* Wka = (short*)(ws + 3 * WSZ);
    short* Wva = (short*)(ws + 4 * WSZ);
    short* Wz1 = (short*)(ws + 5 * WSZ);
    short* Wz2 = (short*)(ws + 6 * WSZ);
    short* Wo  = (short*)(ws + 7 * WSZ);
    char* p = ws + 8 * WSZ;
    short* Ahs  = (short*)p; p += ASZ;
    short* Aemb = (short*)p; p += ASZ;
    short* Qb   = (short*)p; p += ASZ;
    short* Kb   = (short*)p; p += ASZ;
    short* Vb   = (short*)p; p += ASZ;
    short* KAb  = (short*)p; p += ASZ;
    short* VAb  = (short*)p; p += ASZ;
    short* Wz1p = (short*)p; p += 80 * 160 * 2;  // padded zt1_w bf16 [80][160]
    short* Wz2p = (short*)p; p += 80 * 96 * 2;   // padded zt2_w bf16 [80][96]
    // aliases (lifetimes disjoint in stream order):
    short* CAT = Ahs;   // (B,2T,E) over Ahs+Aemb   — written after q/k/v/ka/va GEMMs
    short* Y   = KAb;   // (B,2T,E) over KAb+VAb    — written after adapter attn
    short* X2  = Qb;    // written after both attns
    short* X3  = Kb;
    short* S   = Vb;

    if (ws_size < (size_t)(p - ws)) return;   // clean-fail signal

    // casts
    cast_f32_bf16<<<2048, 256, 0, stream>>>(hidden, Ahs,  MTOK * E_ / 4);
    cast_f32_bf16<<<2048, 256, 0, stream>>>(embeds, Aemb, MTOK * E_ / 4);
    cast_f32_bf16<<<512, 256, 0, stream>>>(q_w,  Wq,  E_ * E_ / 4);
    cast_f32_bf16<<<512, 256, 0, stream>>>(k_w,  Wk,  E_ * E_ / 4);
    cast_f32_bf16<<<512, 256, 0, stream>>>(v_w,  Wv,  E_ * E_ / 4);
    cast_f32_bf16<<<512, 256, 0, stream>>>(ka_w, Wka, E_ * E_ / 4);
    cast_f32_bf16<<<512, 256, 0, stream>>>(va_w, Wva, E_ * E_ / 4);
    cast_f32_bf16<<<512, 256, 0, stream>>>(zc1_w, Wz1, E_ * E_ / 4);
    cast_f32_bf16<<<512, 256, 0, stream>>>(zc2_w, Wz2, E_ * E_ / 4);
    cast_f32_bf16<<<512, 256, 0, stream>>>(o_w,  Wo,  E_ * E_ / 4);
    pad_weight<<<(80 * 160 + 255) / 256, 256, 0, stream>>>(zt1_w, Wz1p, 77, 154, 160);
    pad_weight<<<(80 * 96 + 255) / 256, 256, 0, stream>>>(zt2_w, Wz2p, 77, 77, 96);

    const int g154 = (MTOK / BM2) * (E_ / BN2);    // 77*10 = 770 blocks
    const int g308 = (MTOK2 / BM2) * (E_ / BN2);   // 154*10 = 1540 blocks
    // projections
    gemm_bt<1><<<g154, 512, 0, stream>>>(Ahs,  Wq,  q_b,  Qb,  E_, 0.125f); // (x@Wq^T+b)*scale
    gemm_bt<0><<<g154, 512, 0, stream>>>(Ahs,  Wk,  k_b,  Kb,  E_, 1.f);
    gemm_bt<0><<<g154, 512, 0, stream>>>(Ahs,  Wv,  v_b,  Vb,  E_, 1.f);
    gemm_bt<0><<<g154, 512, 0, stream>>>(Aemb, Wka, ka_b, KAb, E_, 1.f);
    gemm_bt<0><<<g154, 512, 0, stream>>>(Aemb, Wva, va_b, VAb, E_, 1.f);
    // fused attention (both passes): adapter rows [0,77), self rows [77,154) of CAT
    attn_mfma<<<B_ * H_, 64, 0, stream>>>(Qb, Kb, Vb, KAb, VAb, CAT);
    // zipper
    gemm_bt<2><<<g308, 512, 0, stream>>>(CAT, Wz1, zc1_b, Y, E_, 1.f);      // gelu
    mixer_mfma<154, 160, 168, true, false><<<dim3(E_ / 64, B_), 256, 0, stream>>>(
        Y, Wz1p, zt1_b, nullptr, X2);
    gemm_bt<0><<<g154, 512, 0, stream>>>(X2, Wz2, zc2_b, X3, E_, 1.f);
    mixer_mfma<77, 96, 104, false, true><<<dim3(E_ / 64, B_), 256, 0, stream>>>(
        X3, Wz2p, zt2_b, CAT, S);
    // output projection -> fp32 d_out
    gemm_bt<3><<<g154, 512, 0, stream>>>(S, Wo, o_b, (float*)d_out, E_, 1.f);
}

// Round 11
// 1098.760 us; speedup vs baseline: 1.3573x; 1.3573x over previous
//
#include <hip/hip_runtime.h>
#include <stdint.h>

#define B_    256
#define T_    77
#define E_    1280
#define H_    20
#define T2_   154
#define MTOK  19712   // B_*T_
#define MTOK2 39424   // B_*T2_

typedef float f32x4 __attribute__((ext_vector_type(4)));
typedef short bf16x8 __attribute__((ext_vector_type(8)));

__device__ inline float bf2f(short s) {
    return __uint_as_float(((unsigned)(unsigned short)s) << 16);
}
__device__ inline short f2bf(float f) {
    unsigned u = __float_as_uint(f);
    u += 0x7fff + ((u >> 16) & 1);   // RNE
    return (short)(u >> 16);
}
__device__ inline float gelu_tanh(float x) {   // jax.nn.gelu approximate=True
    float x3 = x * x * x;
    return 0.5f * x * (1.0f + tanhf(0.7978845608028654f * (x + 0.044715f * x3)));
}

// ---------------- fp32 -> bf16 cast ----------------
__global__ void cast_f32_bf16(const float* __restrict__ in, short* __restrict__ out, int n4) {
    int i = blockIdx.x * blockDim.x + threadIdx.x;
    int stride = gridDim.x * blockDim.x;
    for (; i < n4; i += stride) {
        float4 v = reinterpret_cast<const float4*>(in)[i];
        short4 o;
        o.x = f2bf(v.x); o.y = f2bf(v.y); o.z = f2bf(v.z); o.w = f2bf(v.w);
        reinterpret_cast<short4*>(out)[i] = o;
    }
}

// ---------------- pad token-mix weight: fp32 (rows x cols) -> bf16 [80][KP], zero pad ----
__global__ void pad_weight(const float* __restrict__ W, short* __restrict__ Wp,
                           int rows, int cols, int KP) {
    int i = blockIdx.x * 256 + threadIdx.x;
    if (i >= 80 * KP) return;
    int t = i / KP, s = i - t * KP;
    Wp[i] = (t < rows && s < cols) ? f2bf(W[t * cols + s]) : (short)0;
}

// ======================= R9-proven GEMM core (128x128, BK=64) ====================
// 4 waves (each 64x64), global_load_lds w=16, T1 bijective XCD swizzle,
// T2 both-sides LDS XOR swizzle (R9: conflicts 4.7e7 -> 0).
// R10's 256x128 dbuf variant REVERTED: 96KB LDS -> 1 block/CU, MfmaUtil 17.9%,
// 300 us/GEMM (m132-class occupancy regression).
#define GEMM_CORE(A_, W_, KDIM, ACC)                                                   \
    const int rsub = lane >> 3;                                                        \
    const int col  = (((lane & 7) ^ rsub) & 7) * 8;                                    \
    const int swz  = (lane & 7) << 3;                                                  \
    for (int kt = 0; kt < (KDIM); kt += 64) {                                          \
        __syncthreads();                                                               \
        _Pragma("unroll")                                                              \
        for (int i = 0; i < 4; ++i) {                                                  \
            int chunk = i * 4 + wave;                                                  \
            int row = chunk * 8 + rsub;                                                \
            const short* ga = (A_) + (arow0 + row) * (KDIM) + kt + col;                \
            const short* gb = (W_) + (brow0 + row) * (KDIM) + kt + col;                \
            __builtin_amdgcn_global_load_lds(                                          \
                (const __attribute__((address_space(1))) unsigned int*)ga,             \
                (__attribute__((address_space(3))) unsigned int*)&Als[chunk * 512],    \
                16, 0, 0);                                                             \
            __builtin_amdgcn_global_load_lds(                                          \
                (const __attribute__((address_space(1))) unsigned int*)gb,             \
                (__attribute__((address_space(3))) unsigned int*)&Bls[chunk * 512],    \
                16, 0, 0);                                                             \
        }                                                                              \
        __syncthreads();                                                               \
        _Pragma("unroll")                                                              \
        for (int kk = 0; kk < 2; ++kk) {                                               \
            bf16x8 af[4], bfr[4];                                                      \
            _Pragma("unroll")                                                          \
            for (int mi = 0; mi < 4; ++mi)                                             \
                af[mi] = *reinterpret_cast<const bf16x8*>(                             \
                    &Als[(((wm + mi * 16 + (lane & 15)) * 64 + kk * 32 +               \
                           (lane >> 4) * 8)) ^ swz]);                                  \
            _Pragma("unroll")                                                          \
            for (int nj = 0; nj < 4; ++nj)                                             \
                bfr[nj] = *reinterpret_cast<const bf16x8*>(                            \
                    &Bls[(((wn + nj * 16 + (lane & 15)) * 64 + kk * 32 +               \
                           (lane >> 4) * 8)) ^ swz]);                                  \
            _Pragma("unroll")                                                          \
            for (int mi = 0; mi < 4; ++mi)                                             \
                _Pragma("unroll")                                                      \
                for (int nj = 0; nj < 4; ++nj)                                         \
                    ACC[mi][nj] = __builtin_amdgcn_mfma_f32_16x16x32_bf16(             \
                        af[mi], bfr[nj], ACC[mi][nj], 0, 0, 0);                        \
        }                                                                              \
    }

// ---------------- generic GEMM: C[M,N=E] = A[M,K] @ W[N,K]^T (+epilogue) --------
// EPI: 0 = +bias -> bf16 ; 2 = gelu(+bias) -> bf16 ; 3 = +bias -> fp32
template<int EPI>
__global__ void gemm_bt(const short* __restrict__ A, const short* __restrict__ W,
                        const float* __restrict__ bias, void* __restrict__ Cout,
                        int K) {
    const int N = E_;
    const int NBN = E_ / 128;            // 10 N-tiles
    __shared__ short Als[128 * 64];
    __shared__ short Bls[128 * 64];
    const int tid  = threadIdx.x;
    const int wave = tid >> 6, lane = tid & 63;

    const int nwg = gridDim.x;
    const int qq = nwg >> 3, rr = nwg & 7;
    const int x = blockIdx.x & 7, ii = blockIdx.x >> 3;
    const int L = (x < rr ? x * (qq + 1) : rr * (qq + 1) + (x - rr) * qq) + ii;
    const int bm = L / NBN, bn = L % NBN;

    const int wm = (wave >> 1) * 64, wn = (wave & 1) * 64;
    f32x4 acc[4][4] = {};
    const long arow0 = (long)bm * 128;
    const long brow0 = (long)bn * 128;

    GEMM_CORE(A, W, K, acc)

#pragma unroll
    for (int mi = 0; mi < 4; ++mi) {
#pragma unroll
        for (int nj = 0; nj < 4; ++nj) {
            int gcol = bn * 128 + wn + nj * 16 + (lane & 15);
            float bv = bias[gcol];
#pragma unroll
            for (int r = 0; r < 4; ++r) {
                long grow = arow0 + wm + mi * 16 + (lane >> 4) * 4 + r;
                float v = acc[mi][nj][r] + bv;
                if (EPI == 2) v = gelu_tanh(v);
                if (EPI == 3) ((float*)Cout)[grow * N + gcol] = v;
                else          ((short*)Cout)[grow * N + gcol] = f2bf(v);
            }
        }
    }
}

// ---------------- fused projection GEMM: N = NSEG*E, seg-selected bias/out ------
// W is NSEG concatenated [E][E] weights (contiguous in ws). seg = bn/10 is
// wave-uniform (1280 % 128 == 0). seg 0 applies scale s0 (Q: *0.125).
template<int NSEG>
__global__ void gemm_proj(const short* __restrict__ A, const short* __restrict__ W,
                          const float* __restrict__ b0, const float* __restrict__ b1,
                          const float* __restrict__ b2,
                          short* __restrict__ o0, short* __restrict__ o1,
                          short* __restrict__ o2, float s0) {
    const int NBN = NSEG * (E_ / 128);
    __shared__ short Als[128 * 64];
    __shared__ short Bls[128 * 64];
    const int tid  = threadIdx.x;
    const int wave = tid >> 6, lane = tid & 63;

    const int nwg = gridDim.x;
    const int qq = nwg >> 3, rr = nwg & 7;
    const int x = blockIdx.x & 7, ii = blockIdx.x >> 3;
    const int L = (x < rr ? x * (qq + 1) : rr * (qq + 1) + (x - rr) * qq) + ii;
    const int bm = L / NBN, bn = L % NBN;

    const int wm = (wave >> 1) * 64, wn = (wave & 1) * 64;
    f32x4 acc[4][4] = {};
    const long arow0 = (long)bm * 128;
    const long brow0 = (long)bn * 128;      // row into concatenated W
    const int K = E_;

    GEMM_CORE(A, W, K, acc)

    const int seg = bn / (E_ / 128);
    const float* bias = seg == 0 ? b0 : (seg == 1 ? b1 : b2);
    short* out = seg == 0 ? o0 : (seg == 1 ? o1 : o2);
    const float scl = seg == 0 ? s0 : 1.f;
    const int bnl = bn - seg * (E_ / 128);
#pragma unroll
    for (int mi = 0; mi < 4; ++mi) {
#pragma unroll
        for (int nj = 0; nj < 4; ++nj) {
            int gcol = bnl * 128 + wn + nj * 16 + (lane & 15);
            float bv = bias[gcol];
#pragma unroll
            for (int r = 0; r < 4; ++r) {
                long grow = arow0 + wm + mi * 16 + (lane >> 4) * 4 + r;
                out[grow * E_ + gcol] = f2bf((acc[mi][nj][r] + bv) * scl);
            }
        }
    }
}

// ---------------- MFMA token mixer ----------------
template<int SIN, int KP, int PS, bool GELU, bool RESID>
__global__ void mixer_mfma(const short* __restrict__ IN, const short* __restrict__ Wp,
                           const float* __restrict__ bias, const short* __restrict__ Cat,
                           short* __restrict__ OUT) {
    __shared__ short lsT[64 * PS];
    const int e0 = blockIdx.x * 64;
    const int b  = blockIdx.y;
    const int tid = threadIdx.x, wave = tid >> 6, lane = tid & 63;

    const int eg = tid & 7;
    const int sl = tid >> 3;
    for (int sb = sl; sb < KP; sb += 32) {
        if (sb < SIN) {
            bf16x8 v = *reinterpret_cast<const bf16x8*>(
                &IN[((long)b * SIN + sb) * E_ + e0 + eg * 8]);
#pragma unroll
            for (int i = 0; i < 8; ++i)
                lsT[(eg * 8 + i) * PS + sb] = v[i];
        } else {
#pragma unroll
            for (int i = 0; i < 8; ++i)
                lsT[(eg * 8 + i) * PS + sb] = 0;
        }
    }
    __syncthreads();

    const int ebase = wave * 16;
    f32x4 acc[5] = {};
#pragma unroll
    for (int ks = 0; ks < KP / 32; ++ks) {
        bf16x8 bfr = *reinterpret_cast<const bf16x8*>(
            &lsT[(ebase + (lane & 15)) * PS + ks * 32 + (lane >> 4) * 8]);
#pragma unroll
        for (int mt = 0; mt < 5; ++mt) {
            bf16x8 af = *reinterpret_cast<const bf16x8*>(
                &Wp[(mt * 16 + (lane & 15)) * KP + ks * 32 + (lane >> 4) * 8]);
            acc[mt] = __builtin_amdgcn_mfma_f32_16x16x32_bf16(af, bfr, acc[mt], 0, 0, 0);
        }
    }

    const int e = e0 + ebase + (lane & 15);
#pragma unroll
    for (int mt = 0; mt < 5; ++mt) {
#pragma unroll
        for (int r = 0; r < 4; ++r) {
            int t = mt * 16 + (lane >> 4) * 4 + r;
            if (t < T_) {
                float v = acc[mt][r] + bias[t];
                if (GELU) v = gelu_tanh(v);
                if (RESID) v += bf2f(Cat[((long)b * T2_ + T_ + t) * E_ + e]);
                OUT[((long)b * T_ + t) * E_ + e] = f2bf(v);
            }
        }
    }
}

// ---------------- fused MFMA attention: one WAVE per (b,h), both passes ----------------
#define ASTR 104   // LDS row stride (shorts): 16B-aligned, <=2-way banks on b128
__global__ __launch_bounds__(64, 1)
void attn_mfma(const short* __restrict__ Qm,
               const short* __restrict__ Km, const short* __restrict__ Vm,
               const short* __restrict__ KAm, const short* __restrict__ VAm,
               short* __restrict__ Cat) {
    __shared__ short pls[80 * ASTR];
    __shared__ short vt[64 * ASTR];
    const int hh = blockIdx.x;
    const int b = hh / H_, h = hh % H_;
    const int lane = threadIdx.x & 63;
    const int colbase = lane & 15, g = lane >> 4;
    const long base = ((long)b * T_) * E_ + h * 64;

    for (int pass = 0; pass < 2; ++pass) {
        const short* Kp = pass ? KAm : Km;
        const short* Vp = pass ? VAm : Vm;
        const bool causal = (pass == 0);
        const int rowoff = pass ? 0 : T_;

        {
            int4 z = {0, 0, 0, 0};
#pragma unroll
            for (int it = 0; it < 4; ++it) {
                int idx = it * 64 + lane;
                int row = idx >> 2, cb = idx & 3;
                *reinterpret_cast<int4*>(&vt[row * ASTR + 64 + cb * 8]) = z;
            }
#pragma unroll
            for (int it = 0; it < 3; ++it) {
                int idx = it * 64 + lane;
                if (idx < 160) {
                    int row = idx >> 1, cb = idx & 1;
                    *reinterpret_cast<int4*>(&pls[row * ASTR + 80 + cb * 8]) = z;
                }
            }
        }

        {
            const short* vb = Vp + base + (long)lane * E_;
#pragma unroll
            for (int dg = 0; dg < 8; ++dg) {
                bf16x8 v = *reinterpret_cast<const bf16x8*>(vb + dg * 8);
#pragma unroll
                for (int i = 0; i < 8; ++i) vt[(dg * 8 + i) * ASTR + lane] = v[i];
            }
            if (lane < T_ - 64) {
                const short* vb2 = Vp + base + (long)(64 + lane) * E_;
#pragma unroll
                for (int dg = 0; dg < 8; ++dg) {
                    bf16x8 v = *reinterpret_cast<const bf16x8*>(vb2 + dg * 8);
#pragma unroll
                    for (int i = 0; i < 8; ++i) vt[(dg * 8 + i) * ASTR + 64 + lane] = v[i];
                }
            }
        }

        f32x4 sacc[5][5] = {};
#pragma unroll
        for (int kk = 0; kk < 2; ++kk) {
            bf16x8 qf[5];
#pragma unroll
            for (int mi = 0; mi < 5; ++mi) {
                int t = mi * 16 + colbase; t = t > 76 ? 76 : t;
                qf[mi] = *reinterpret_cast<const bf16x8*>(
                    Qm + base + (long)t * E_ + kk * 32 + g * 8);
            }
#pragma unroll
            for (int nj = 0; nj < 5; ++nj) {
                int s = nj * 16 + colbase; s = s > 76 ? 76 : s;
                bf16x8 kf = *reinterpret_cast<const bf16x8*>(
                    Kp + base + (long)s * E_ + kk * 32 + g * 8);
#pragma unroll
                for (int mi = 0; mi < 5; ++mi)
                    sacc[mi][nj] = __builtin_amdgcn_mfma_f32_16x16x32_bf16(
                        qf[mi], kf, sacc[mi][nj], 0, 0, 0);
            }
        }

        float inv[5][4];
#pragma unroll
        for (int mi = 0; mi < 5; ++mi) {
#pragma unroll
            for (int r = 0; r < 4; ++r) {
                int t = mi * 16 + g * 4 + r;
                float mx = -3.0e38f;
#pragma unroll
                for (int nj = 0; nj < 5; ++nj) {
                    int s = nj * 16 + colbase;
                    bool ok = causal ? (s <= t) : (s < T_);
                    if (ok) mx = fmaxf(mx, sacc[mi][nj][r]);
                }
#pragma unroll
                for (int o = 1; o <= 8; o <<= 1) mx = fmaxf(mx, __shfl_xor(mx, o));
                float sum = 0.f;
#pragma unroll
                for (int nj = 0; nj < 5; ++nj) {
                    int s = nj * 16 + colbase;
                    bool ok = causal ? (s <= t) : (s < T_);
                    float pv = ok ? __expf(sacc[mi][nj][r] - mx) : 0.f;
                    sacc[mi][nj][r] = pv;
                    sum += pv;
                }
#pragma unroll
                for (int o = 1; o <= 8; o <<= 1) sum += __shfl_xor(sum, o);
                inv[mi][r] = 1.0f / sum;
            }
        }

#pragma unroll
        for (int mi = 0; mi < 5; ++mi)
#pragma unroll
            for (int nj = 0; nj < 5; ++nj)
#pragma unroll
                for (int r = 0; r < 4; ++r)
                    pls[(mi * 16 + g * 4 + r) * ASTR + nj * 16 + colbase] =
                        f2bf(sacc[mi][nj][r]);

        f32x4 cacc[5][4] = {};
#pragma unroll
        for (int ks = 0; ks < 3; ++ks) {
            bf16x8 pa[5];
#pragma unroll
            for (int mi = 0; mi < 5; ++mi)
                pa[mi] = *reinterpret_cast<const bf16x8*>(
                    &pls[(mi * 16 + colbase) * ASTR + ks * 32 + g * 8]);
#pragma unroll
            for (int nd = 0; nd < 4; ++nd) {
                bf16x8 vf = *reinterpret_cast<const bf16x8*>(
                    &vt[(nd * 16 + colbase) * ASTR + ks * 32 + g * 8]);
#pragma unroll
                for (int mi = 0; mi < 5; ++mi)
                    cacc[mi][nd] = __builtin_amdgcn_mfma_f32_16x16x32_bf16(
                        pa[mi], vf, cacc[mi][nd], 0, 0, 0);
            }
        }

#pragma unroll
        for (int mi = 0; mi < 5; ++mi)
#pragma unroll
            for (int nd = 0; nd < 4; ++nd)
#pragma unroll
                for (int r = 0; r < 4; ++r) {
                    int t = mi * 16 + g * 4 + r;
                    if (t < T_) {
                        float val = cacc[mi][nd][r] * inv[mi][r];
                        Cat[((long)b * T2_ + rowoff + t) * E_ + h * 64 + nd * 16 + colbase] =
                            f2bf(val);
                    }
                }
    }
}

extern "C" void kernel_launch(void* const* d_in, const int* in_sizes, int n_in,
                              void* d_out, int out_size, void* d_ws, size_t ws_size,
                              hipStream_t stream) {
    const float* hidden = (const float*)d_in[0];
    const float* embeds = (const float*)d_in[1];
    // d_in[2] causal_mask unused (exactly triu(-1e9) -> applied analytically)
    const float* q_w  = (const float*)d_in[3];  const float* q_b  = (const float*)d_in[4];
    const float* k_w  = (const float*)d_in[5];  const float* k_b  = (const float*)d_in[6];
    const float* v_w  = (const float*)d_in[7];  const float* v_b  = (const float*)d_in[8];
    const float* o_w  = (const float*)d_in[9];  const float* o_b  = (const float*)d_in[10];
    const float* ka_w = (const float*)d_in[11]; const float* ka_b = (const float*)d_in[12];
    const float* va_w = (const float*)d_in[13]; const float* va_b = (const float*)d_in[14];
    const float* zc1_w = (const float*)d_in[15]; const float* zc1_b = (const float*)d_in[16];
    const float* zt1_w = (const float*)d_in[17]; const float* zt1_b = (const float*)d_in[18];
    const float* zc2_w = (const float*)d_in[19]; const float* zc2_b = (const float*)d_in[20];
    const float* zt2_w = (const float*)d_in[21]; const float* zt2_b = (const float*)d_in[22];

    char* ws = (char*)d_ws;
    const size_t WSZ = (size_t)E_ * E_ * 2;      // 3,276,800 B per weight
    const size_t ASZ = (size_t)MTOK * E_ * 2;    // 50,462,720 B per activation
    short* Wq  = (short*)(ws + 0 * WSZ);         // Wq|Wk|Wv contiguous = [3840][1280]
    short* Wk  = (short*)(ws + 1 * WSZ);
    short* Wv  = (short*)(ws + 2 * WSZ);
    short* Wka = (short*)(ws + 3 * WSZ);         // Wka|Wva contiguous = [2560][1280]
    short* Wva = (short*)(ws + 4 * WSZ);
    short* Wz1 = (short*)(ws + 5 * WSZ);
    short* Wz2 = (short*)(ws + 6 * WSZ);
    short* Wo  = (short*)(ws + 7 * WSZ);
    char* p = ws + 8 * WSZ;
    short* Ahs  = (short*)p; p += ASZ;
    short* Aemb = (short*)p; p += ASZ;
    short* Qb   = (short*)p; p += ASZ;
    short* Kb   = (short*)p; p += ASZ;
    short* Vb   = (short*)p; p += ASZ;
    short* KAb  = (short*)p; p += ASZ;
    short* VAb  = (short*)p; p += ASZ;
    short* Wz1p = (short*)p; p += 80 * 160 * 2;  // padded zt1_w bf16 [80][160]
    short* Wz2p = (short*)p; p += 80 * 96 * 2;   // padded zt2_w bf16 [80][96]
    // aliases (lifetimes disjoint in stream order):
    short* CAT = Ahs;   // (B,2T,E) over Ahs+Aemb   — written after projections
    short* Y   = KAb;   // (B,2T,E) over KAb+VAb    — written after attention
    short* X2  = Qb;
    short* X3  = Kb;
    short* S   = Vb;

    if (ws_size < (size_t)(p - ws)) return;   // clean-fail signal

    // casts
    cast_f32_bf16<<<2048, 256, 0, stream>>>(hidden, Ahs,  MTOK * E_ / 4);
    cast_f32_bf16<<<2048, 256, 0, stream>>>(embeds, Aemb, MTOK * E_ / 4);
    cast_f32_bf16<<<512, 256, 0, stream>>>(q_w,  Wq,  E_ * E_ / 4);
    cast_f32_bf16<<<512, 256, 0, stream>>>(k_w,  Wk,  E_ * E_ / 4);
    cast_f32_bf16<<<512, 256, 0, stream>>>(v_w,  Wv,  E_ * E_ / 4);
    cast_f32_bf16<<<512, 256, 0, stream>>>(ka_w, Wka, E_ * E_ / 4);
    cast_f32_bf16<<<512, 256, 0, stream>>>(va_w, Wva, E_ * E_ / 4);
    cast_f32_bf16<<<512, 256, 0, stream>>>(zc1_w, Wz1, E_ * E_ / 4);
    cast_f32_bf16<<<512, 256, 0, stream>>>(zc2_w, Wz2, E_ * E_ / 4);
    cast_f32_bf16<<<512, 256, 0, stream>>>(o_w,  Wo,  E_ * E_ / 4);
    pad_weight<<<(80 * 160 + 255) / 256, 256, 0, stream>>>(zt1_w, Wz1p, 77, 154, 160);
    pad_weight<<<(80 * 96 + 255) / 256, 256, 0, stream>>>(zt2_w, Wz2p, 77, 77, 96);

    const int gQKV  = (MTOK / 128) * (3 * E_ / 128);   // 154*30 = 4620
    const int gKAVA = (MTOK / 128) * (2 * E_ / 128);   // 154*20 = 3080
    const int g154  = (MTOK / 128) * (E_ / 128);       // 1540
    const int g308  = (MTOK2 / 128) * (E_ / 128);      // 3080
    // fused projections: QKV from hidden (Q scaled by 0.125), KA/VA from embeds
    gemm_proj<3><<<gQKV, 256, 0, stream>>>(Ahs, Wq, q_b, k_b, v_b,
                                           Qb, Kb, Vb, 0.125f);
    gemm_proj<2><<<gKAVA, 256, 0, stream>>>(Aemb, Wka, ka_b, va_b, nullptr,
                                            KAb, VAb, nullptr, 1.f);
    // fused attention (both passes): adapter rows [0,77), self rows [77,154) of CAT
    attn_mfma<<<B_ * H_, 64, 0, stream>>>(Qb, Kb, Vb, KAb, VAb, CAT);
    // zipper
    gemm_bt<2><<<g308, 256, 0, stream>>>(CAT, Wz1, zc1_b, Y, E_);      // gelu
    mixer_mfma<154, 160, 168, true, false><<<dim3(E_ / 64, B_), 256, 0, stream>>>(
        Y, Wz1p, zt1_b, nullptr, X2);
    gemm_bt<0><<<g154, 256, 0, stream>>>(X2, Wz2, zc2_b, X3, E_);
    mixer_mfma<77, 96, 104, false, true><<<dim3(E_ / 64, B_), 256, 0, stream>>>(
        X3, Wz2p, zt2_b, CAT, S);
    // output projection -> fp32 d_out
    gemm_bt<3><<<g154, 256, 0, stream>>>(S, Wo, o_b, (float*)d_out, E_);
}

// Round 12
// 1049.220 us; speedup vs baseline: 1.4214x; 1.0472x over previous
//
#include <hip/hip_runtime.h>
#include <stdint.h>

#define B_    256
#define T_    77
#define E_    1280
#define H_    20
#define T2_   154
#define MTOK  19712   // B_*T_
#define MTOK2 39424   // B_*T2_

typedef float f32x4 __attribute__((ext_vector_type(4)));
typedef short bf16x8 __attribute__((ext_vector_type(8)));

__device__ inline float bf2f(short s) {
    return __uint_as_float(((unsigned)(unsigned short)s) << 16);
}
__device__ inline short f2bf(float f) {
    unsigned u = __float_as_uint(f);
    u += 0x7fff + ((u >> 16) & 1);   // RNE
    return (short)(u >> 16);
}
__device__ inline float gelu_tanh(float x) {   // jax.nn.gelu approximate=True
    float x3 = x * x * x;
    return 0.5f * x * (1.0f + tanhf(0.7978845608028654f * (x + 0.044715f * x3)));
}

// ---------------- fp32 -> bf16 cast ----------------
__global__ void cast_f32_bf16(const float* __restrict__ in, short* __restrict__ out, int n4) {
    int i = blockIdx.x * blockDim.x + threadIdx.x;
    int stride = gridDim.x * blockDim.x;
    for (; i < n4; i += stride) {
        float4 v = reinterpret_cast<const float4*>(in)[i];
        short4 o;
        o.x = f2bf(v.x); o.y = f2bf(v.y); o.z = f2bf(v.z); o.w = f2bf(v.w);
        reinterpret_cast<short4*>(out)[i] = o;
    }
}

// ---------------- merged 8-weight cast: out regions contiguous in ws ----------------
__global__ void cast8_f32_bf16(const float* __restrict__ s0, const float* __restrict__ s1,
                               const float* __restrict__ s2, const float* __restrict__ s3,
                               const float* __restrict__ s4, const float* __restrict__ s5,
                               const float* __restrict__ s6, const float* __restrict__ s7,
                               short* __restrict__ out) {
    const int per = E_ * E_ / 4;    // 409600 float4 per weight
    int i = blockIdx.x * blockDim.x + threadIdx.x;
    int stride = gridDim.x * blockDim.x;
    for (; i < 8 * per; i += stride) {
        int w = i / per, j = i - w * per;
        const float* src = w == 0 ? s0 : w == 1 ? s1 : w == 2 ? s2 : w == 3 ? s3
                         : w == 4 ? s4 : w == 5 ? s5 : w == 6 ? s6 : s7;
        float4 v = reinterpret_cast<const float4*>(src)[j];
        short4 o;
        o.x = f2bf(v.x); o.y = f2bf(v.y); o.z = f2bf(v.z); o.w = f2bf(v.w);
        reinterpret_cast<short4*>(out)[i] = o;
    }
}

// ---------------- pad token-mix weight: fp32 (rows x cols) -> bf16 [80][KP], zero pad ----
__global__ void pad_weight(const float* __restrict__ W, short* __restrict__ Wp,
                           int rows, int cols, int KP) {
    int i = blockIdx.x * 256 + threadIdx.x;
    if (i >= 80 * KP) return;
    int t = i / KP, s = i - t * KP;
    Wp[i] = (t < rows && s < cols) ? f2bf(W[t * cols + s]) : (short)0;
}

// ======================= R9-proven GEMM core (128x128, BK=64) ====================
// 4 waves (each 64x64), global_load_lds w=16, T1 bijective XCD swizzle,
// T2 both-sides LDS XOR swizzle (R9: conflicts 4.7e7 -> 0).
#define GEMM_CORE(A_, W_, KDIM, ACC)                                                   \
    const int rsub = lane >> 3;                                                        \
    const int col  = (((lane & 7) ^ rsub) & 7) * 8;                                    \
    const int swz  = (lane & 7) << 3;                                                  \
    for (int kt = 0; kt < (KDIM); kt += 64) {                                          \
        __syncthreads();                                                               \
        _Pragma("unroll")                                                              \
        for (int i = 0; i < 4; ++i) {                                                  \
            int chunk = i * 4 + wave;                                                  \
            int row = chunk * 8 + rsub;                                                \
            const short* ga = (A_) + (arow0 + row) * (KDIM) + kt + col;                \
            const short* gb = (W_) + (brow0 + row) * (KDIM) + kt + col;                \
            __builtin_amdgcn_global_load_lds(                                          \
                (const __attribute__((address_space(1))) unsigned int*)ga,             \
                (__attribute__((address_space(3))) unsigned int*)&Als[chunk * 512],    \
                16, 0, 0);                                                             \
            __builtin_amdgcn_global_load_lds(                                          \
                (const __attribute__((address_space(1))) unsigned int*)gb,             \
                (__attribute__((address_space(3))) unsigned int*)&Bls[chunk * 512],    \
                16, 0, 0);                                                             \
        }                                                                              \
        __syncthreads();                                                               \
        _Pragma("unroll")                                                              \
        for (int kk = 0; kk < 2; ++kk) {                                               \
            bf16x8 af[4], bfr[4];                                                      \
            _Pragma("unroll")                                                          \
            for (int mi = 0; mi < 4; ++mi)                                             \
                af[mi] = *reinterpret_cast<const bf16x8*>(                             \
                    &Als[(((wm + mi * 16 + (lane & 15)) * 64 + kk * 32 +               \
                           (lane >> 4) * 8)) ^ swz]);                                  \
            _Pragma("unroll")                                                          \
            for (int nj = 0; nj < 4; ++nj)                                             \
                bfr[nj] = *reinterpret_cast<const bf16x8*>(                            \
                    &Bls[(((wn + nj * 16 + (lane & 15)) * 64 + kk * 32 +               \
                           (lane >> 4) * 8)) ^ swz]);                                  \
            _Pragma("unroll")                                                          \
            for (int mi = 0; mi < 4; ++mi)                                             \
                _Pragma("unroll")                                                      \
                for (int nj = 0; nj < 4; ++nj)                                         \
                    ACC[mi][nj] = __builtin_amdgcn_mfma_f32_16x16x32_bf16(             \
                        af[mi], bfr[nj], ACC[mi][nj], 0, 0, 0);                        \
        }                                                                              \
    }

// ---------------- generic GEMM: C[M,N=E] = A[M,K] @ W[N,K]^T (+epilogue) --------
// EPI: 0 = +bias -> bf16 ; 2 = gelu(+bias) -> bf16 ; 3 = +bias -> fp32
template<int EPI>
__global__ void gemm_bt(const short* __restrict__ A, const short* __restrict__ W,
                        const float* __restrict__ bias, void* __restrict__ Cout,
                        int K) {
    const int N = E_;
    const int NBN = E_ / 128;            // 10 N-tiles
    __shared__ short Als[128 * 64];
    __shared__ short Bls[128 * 64];
    const int tid  = threadIdx.x;
    const int wave = tid >> 6, lane = tid & 63;

    const int nwg = gridDim.x;
    const int qq = nwg >> 3, rr = nwg & 7;
    const int x = blockIdx.x & 7, ii = blockIdx.x >> 3;
    const int L = (x < rr ? x * (qq + 1) : rr * (qq + 1) + (x - rr) * qq) + ii;
    const int bm = L / NBN, bn = L % NBN;

    const int wm = (wave >> 1) * 64, wn = (wave & 1) * 64;
    f32x4 acc[4][4] = {};
    const long arow0 = (long)bm * 128;
    const long brow0 = (long)bn * 128;

    GEMM_CORE(A, W, K, acc)

#pragma unroll
    for (int mi = 0; mi < 4; ++mi) {
#pragma unroll
        for (int nj = 0; nj < 4; ++nj) {
            int gcol = bn * 128 + wn + nj * 16 + (lane & 15);
            float bv = bias[gcol];
#pragma unroll
            for (int r = 0; r < 4; ++r) {
                long grow = arow0 + wm + mi * 16 + (lane >> 4) * 4 + r;
                float v = acc[mi][nj][r] + bv;
                if (EPI == 2) v = gelu_tanh(v);
                if (EPI == 3) ((float*)Cout)[grow * N + gcol] = v;
                else          ((short*)Cout)[grow * N + gcol] = f2bf(v);
            }
        }
    }
}

// ---------------- fused projection GEMM, SEG-MAJOR ordering ----------------
// W is NSEG concatenated [E][E] weights. R11 bug: bn-fast over NSEG*10 N-tiles
// put the full 9.8 MB fused W in each XCD's concurrent working set -> L2 thrash
// (FETCH 613 MB). Fix: seg OUTERMOST (L/1540), bm-major/bn-fast within seg ->
// concurrent W working set = one seg = 3.3 MB < 4 MB L2.
template<int NSEG>
__global__ void gemm_proj(const short* __restrict__ A, const short* __restrict__ W,
                          const float* __restrict__ b0, const float* __restrict__ b1,
                          const float* __restrict__ b2,
                          short* __restrict__ o0, short* __restrict__ o1,
                          short* __restrict__ o2, float s0) {
    const int PB = (MTOK / 128) * (E_ / 128);   // 1540 blocks per segment
    __shared__ short Als[128 * 64];
    __shared__ short Bls[128 * 64];
    const int tid  = threadIdx.x;
    const int wave = tid >> 6, lane = tid & 63;

    const int nwg = gridDim.x;
    const int qq = nwg >> 3, rr = nwg & 7;
    const int x = blockIdx.x & 7, ii = blockIdx.x >> 3;
    const int L = (x < rr ? x * (qq + 1) : rr * (qq + 1) + (x - rr) * qq) + ii;
    const int seg = L / PB;
    const int rem = L - seg * PB;
    const int bm = rem / (E_ / 128), bnl = rem % (E_ / 128);

    const int wm = (wave >> 1) * 64, wn = (wave & 1) * 64;
    f32x4 acc[4][4] = {};
    const long arow0 = (long)bm * 128;
    const long brow0 = (long)seg * E_ + bnl * 128;   // row into concatenated W
    const int K = E_;

    GEMM_CORE(A, W, K, acc)

    const float* bias = seg == 0 ? b0 : (seg == 1 ? b1 : b2);
    short* out = seg == 0 ? o0 : (seg == 1 ? o1 : o2);
    const float scl = seg == 0 ? s0 : 1.f;
#pragma unroll
    for (int mi = 0; mi < 4; ++mi) {
#pragma unroll
        for (int nj = 0; nj < 4; ++nj) {
            int gcol = bnl * 128 + wn + nj * 16 + (lane & 15);
            float bv = bias[gcol];
#pragma unroll
            for (int r = 0; r < 4; ++r) {
                long grow = arow0 + wm + mi * 16 + (lane >> 4) * 4 + r;
                out[grow * E_ + gcol] = f2bf((acc[mi][nj][r] + bv) * scl);
            }
        }
    }
}

// ---------------- MFMA token mixer ----------------
template<int SIN, int KP, int PS, bool GELU, bool RESID>
__global__ void mixer_mfma(const short* __restrict__ IN, const short* __restrict__ Wp,
                           const float* __restrict__ bias, const short* __restrict__ Cat,
                           short* __restrict__ OUT) {
    __shared__ short lsT[64 * PS];
    const int e0 = blockIdx.x * 64;
    const int b  = blockIdx.y;
    const int tid = threadIdx.x, wave = tid >> 6, lane = tid & 63;

    const int eg = tid & 7;
    const int sl = tid >> 3;
    for (int sb = sl; sb < KP; sb += 32) {
        if (sb < SIN) {
            bf16x8 v = *reinterpret_cast<const bf16x8*>(
                &IN[((long)b * SIN + sb) * E_ + e0 + eg * 8]);
#pragma unroll
            for (int i = 0; i < 8; ++i)
                lsT[(eg * 8 + i) * PS + sb] = v[i];
        } else {
#pragma unroll
            for (int i = 0; i < 8; ++i)
                lsT[(eg * 8 + i) * PS + sb] = 0;
        }
    }
    __syncthreads();

    const int ebase = wave * 16;
    f32x4 acc[5] = {};
#pragma unroll
    for (int ks = 0; ks < KP / 32; ++ks) {
        bf16x8 bfr = *reinterpret_cast<const bf16x8*>(
            &lsT[(ebase + (lane & 15)) * PS + ks * 32 + (lane >> 4) * 8]);
#pragma unroll
        for (int mt = 0; mt < 5; ++mt) {
            bf16x8 af = *reinterpret_cast<const bf16x8*>(
                &Wp[(mt * 16 + (lane & 15)) * KP + ks * 32 + (lane >> 4) * 8]);
            acc[mt] = __builtin_amdgcn_mfma_f32_16x16x32_bf16(af, bfr, acc[mt], 0, 0, 0);
        }
    }

    const int e = e0 + ebase + (lane & 15);
#pragma unroll
    for (int mt = 0; mt < 5; ++mt) {
#pragma unroll
        for (int r = 0; r < 4; ++r) {
            int t = mt * 16 + (lane >> 4) * 4 + r;
            if (t < T_) {
                float v = acc[mt][r] + bias[t];
                if (GELU) v = gelu_tanh(v);
                if (RESID) v += bf2f(Cat[((long)b * T2_ + T_ + t) * E_ + e]);
                OUT[((long)b * T_ + t) * E_ + e] = f2bf(v);
            }
        }
    }
}

// ---------------- fused MFMA attention: one WAVE per (b,h), both passes ----------------
#define ASTR 104   // LDS row stride (shorts): 16B-aligned, <=2-way banks on b128
__global__ __launch_bounds__(64, 1)
void attn_mfma(const short* __restrict__ Qm,
               const short* __restrict__ Km, const short* __restrict__ Vm,
               const short* __restrict__ KAm, const short* __restrict__ VAm,
               short* __restrict__ Cat) {
    __shared__ short pls[80 * ASTR];
    __shared__ short vt[64 * ASTR];
    const int hh = blockIdx.x;
    const int b = hh / H_, h = hh % H_;
    const int lane = threadIdx.x & 63;
    const int colbase = lane & 15, g = lane >> 4;
    const long base = ((long)b * T_) * E_ + h * 64;

    for (int pass = 0; pass < 2; ++pass) {
        const short* Kp = pass ? KAm : Km;
        const short* Vp = pass ? VAm : Vm;
        const bool causal = (pass == 0);
        const int rowoff = pass ? 0 : T_;

        {
            int4 z = {0, 0, 0, 0};
#pragma unroll
            for (int it = 0; it < 4; ++it) {
                int idx = it * 64 + lane;
                int row = idx >> 2, cb = idx & 3;
                *reinterpret_cast<int4*>(&vt[row * ASTR + 64 + cb * 8]) = z;
            }
#pragma unroll
            for (int it = 0; it < 3; ++it) {
                int idx = it * 64 + lane;
                if (idx < 160) {
                    int row = idx >> 1, cb = idx & 1;
                    *reinterpret_cast<int4*>(&pls[row * ASTR + 80 + cb * 8]) = z;
                }
            }
        }

        {
            const short* vb = Vp + base + (long)lane * E_;
#pragma unroll
            for (int dg = 0; dg < 8; ++dg) {
                bf16x8 v = *reinterpret_cast<const bf16x8*>(vb + dg * 8);
#pragma unroll
                for (int i = 0; i < 8; ++i) vt[(dg * 8 + i) * ASTR + lane] = v[i];
            }
            if (lane < T_ - 64) {
                const short* vb2 = Vp + base + (long)(64 + lane) * E_;
#pragma unroll
                for (int dg = 0; dg < 8; ++dg) {
                    bf16x8 v = *reinterpret_cast<const bf16x8*>(vb2 + dg * 8);
#pragma unroll
                    for (int i = 0; i < 8; ++i) vt[(dg * 8 + i) * ASTR + 64 + lane] = v[i];
                }
            }
        }

        f32x4 sacc[5][5] = {};
#pragma unroll
        for (int kk = 0; kk < 2; ++kk) {
            bf16x8 qf[5];
#pragma unroll
            for (int mi = 0; mi < 5; ++mi) {
                int t = mi * 16 + colbase; t = t > 76 ? 76 : t;
                qf[mi] = *reinterpret_cast<const bf16x8*>(
                    Qm + base + (long)t * E_ + kk * 32 + g * 8);
            }
#pragma unroll
            for (int nj = 0; nj < 5; ++nj) {
                int s = nj * 16 + colbase; s = s > 76 ? 76 : s;
                bf16x8 kf = *reinterpret_cast<const bf16x8*>(
                    Kp + base + (long)s * E_ + kk * 32 + g * 8);
#pragma unroll
                for (int mi = 0; mi < 5; ++mi)
                    sacc[mi][nj] = __builtin_amdgcn_mfma_f32_16x16x32_bf16(
                        qf[mi], kf, sacc[mi][nj], 0, 0, 0);
            }
        }

        float inv[5][4];
#pragma unroll
        for (int mi = 0; mi < 5; ++mi) {
#pragma unroll
            for (int r = 0; r < 4; ++r) {
                int t = mi * 16 + g * 4 + r;
                float mx = -3.0e38f;
#pragma unroll
                for (int nj = 0; nj < 5; ++nj) {
                    int s = nj * 16 + colbase;
                    bool ok = causal ? (s <= t) : (s < T_);
                    if (ok) mx = fmaxf(mx, sacc[mi][nj][r]);
                }
#pragma unroll
                for (int o = 1; o <= 8; o <<= 1) mx = fmaxf(mx, __shfl_xor(mx, o));
                float sum = 0.f;
#pragma unroll
                for (int nj = 0; nj < 5; ++nj) {
                    int s = nj * 16 + colbase;
                    bool ok = causal ? (s <= t) : (s < T_);
                    float pv = ok ? __expf(sacc[mi][nj][r] - mx) : 0.f;
                    sacc[mi][nj][r] = pv;
                    sum += pv;
                }
#pragma unroll
                for (int o = 1; o <= 8; o <<= 1) sum += __shfl_xor(sum, o);
                inv[mi][r] = 1.0f / sum;
            }
        }

#pragma unroll
        for (int mi = 0; mi < 5; ++mi)
#pragma unroll
            for (int nj = 0; nj < 5; ++nj)
#pragma unroll
                for (int r = 0; r < 4; ++r)
                    pls[(mi * 16 + g * 4 + r) * ASTR + nj * 16 + colbase] =
                        f2bf(sacc[mi][nj][r]);

        f32x4 cacc[5][4] = {};
#pragma unroll
        for (int ks = 0; ks < 3; ++ks) {
            bf16x8 pa[5];
#pragma unroll
            for (int mi = 0; mi < 5; ++mi)
                pa[mi] = *reinterpret_cast<const bf16x8*>(
                    &pls[(mi * 16 + colbase) * ASTR + ks * 32 + g * 8]);
#pragma unroll
            for (int nd = 0; nd < 4; ++nd) {
                bf16x8 vf = *reinterpret_cast<const bf16x8*>(
                    &vt[(nd * 16 + colbase) * ASTR + ks * 32 + g * 8]);
#pragma unroll
                for (int mi = 0; mi < 5; ++mi)
                    cacc[mi][nd] = __builtin_amdgcn_mfma_f32_16x16x32_bf16(
                        pa[mi], vf, cacc[mi][nd], 0, 0, 0);
            }
        }

#pragma unroll
        for (int mi = 0; mi < 5; ++mi)
#pragma unroll
            for (int nd = 0; nd < 4; ++nd)
#pragma unroll
                for (int r = 0; r < 4; ++r) {
                    int t = mi * 16 + g * 4 + r;
                    if (t < T_) {
                        float val = cacc[mi][nd][r] * inv[mi][r];
                        Cat[((long)b * T2_ + rowoff + t) * E_ + h * 64 + nd * 16 + colbase] =
                            f2bf(val);
                    }
                }
    }
}

extern "C" void kernel_launch(void* const* d_in, const int* in_sizes, int n_in,
                              void* d_out, int out_size, void* d_ws, size_t ws_size,
                              hipStream_t stream) {
    const float* hidden = (const float*)d_in[0];
    const float* embeds = (const float*)d_in[1];
    // d_in[2] causal_mask unused (exactly triu(-1e9) -> applied analytically)
    const float* q_w  = (const float*)d_in[3];  const float* q_b  = (const float*)d_in[4];
    const float* k_w  = (const float*)d_in[5];  const float* k_b  = (const float*)d_in[6];
    const float* v_w  = (const float*)d_in[7];  const float* v_b  = (const float*)d_in[8];
    const float* o_w  = (const float*)d_in[9];  const float* o_b  = (const float*)d_in[10];
    const float* ka_w = (const float*)d_in[11]; const float* ka_b = (const float*)d_in[12];
    const float* va_w = (const float*)d_in[13]; const float* va_b = (const float*)d_in[14];
    const float* zc1_w = (const float*)d_in[15]; const float* zc1_b = (const float*)d_in[16];
    const float* zt1_w = (const float*)d_in[17]; const float* zt1_b = (const float*)d_in[18];
    const float* zc2_w = (const float*)d_in[19]; const float* zc2_b = (const float*)d_in[20];
    const float* zt2_w = (const float*)d_in[21]; const float* zt2_b = (const float*)d_in[22];

    char* ws = (char*)d_ws;
    const size_t WSZ = (size_t)E_ * E_ * 2;      // 3,276,800 B per weight
    const size_t ASZ = (size_t)MTOK * E_ * 2;    // 50,462,720 B per activation
    short* Wq  = (short*)(ws + 0 * WSZ);         // Wq|Wk|Wv contiguous = [3840][1280]
    short* Wka = (short*)(ws + 3 * WSZ);         // Wka|Wva contiguous = [2560][1280]
    short* Wz1 = (short*)(ws + 5 * WSZ);
    short* Wz2 = (short*)(ws + 6 * WSZ);
    short* Wo  = (short*)(ws + 7 * WSZ);
    char* p = ws + 8 * WSZ;
    short* Ahs  = (short*)p; p += ASZ;
    short* Aemb = (short*)p; p += ASZ;
    short* Qb   = (short*)p; p += ASZ;
    short* Kb   = (short*)p; p += ASZ;
    short* Vb   = (short*)p; p += ASZ;
    short* KAb  = (short*)p; p += ASZ;
    short* VAb  = (short*)p; p += ASZ;
    short* Wz1p = (short*)p; p += 80 * 160 * 2;  // padded zt1_w bf16 [80][160]
    short* Wz2p = (short*)p; p += 80 * 96 * 2;   // padded zt2_w bf16 [80][96]
    // aliases (lifetimes disjoint in stream order):
    short* CAT = Ahs;   // (B,2T,E) over Ahs+Aemb   — written after projections
    short* Y   = KAb;   // (B,2T,E) over KAb+VAb    — written after attention
    short* X2  = Qb;
    short* X3  = Kb;
    short* S   = Vb;

    if (ws_size < (size_t)(p - ws)) return;   // clean-fail signal

    // casts (8 weights in one dispatch; out regions contiguous at ws+0..8*WSZ)
    cast_f32_bf16<<<2048, 256, 0, stream>>>(hidden, Ahs,  MTOK * E_ / 4);
    cast_f32_bf16<<<2048, 256, 0, stream>>>(embeds, Aemb, MTOK * E_ / 4);
    cast8_f32_bf16<<<2048, 256, 0, stream>>>(q_w, k_w, v_w, ka_w, va_w, zc1_w, zc2_w, o_w,
                                             Wq);
    pad_weight<<<(80 * 160 + 255) / 256, 256, 0, stream>>>(zt1_w, Wz1p, 77, 154, 160);
    pad_weight<<<(80 * 96 + 255) / 256, 256, 0, stream>>>(zt2_w, Wz2p, 77, 77, 96);

    const int gQKV  = (MTOK / 128) * (3 * E_ / 128);   // 154*30 = 4620
    const int gKAVA = (MTOK / 128) * (2 * E_ / 128);   // 154*20 = 3080
    const int g154  = (MTOK / 128) * (E_ / 128);       // 1540
    const int g308  = (MTOK2 / 128) * (E_ / 128);      // 3080
    // fused projections (seg-major): QKV from hidden (Q scaled), KA/VA from embeds
    gemm_proj<3><<<gQKV, 256, 0, stream>>>(Ahs, Wq, q_b, k_b, v_b,
                                           Qb, Kb, Vb, 0.125f);
    gemm_proj<2><<<gKAVA, 256, 0, stream>>>(Aemb, Wka, ka_b, va_b, nullptr,
                                            KAb, VAb, nullptr, 1.f);
    // fused attention (both passes): adapter rows [0,77), self rows [77,154) of CAT
    attn_mfma<<<B_ * H_, 64, 0, stream>>>(Qb, Kb, Vb, KAb, VAb, CAT);
    // zipper
    gemm_bt<2><<<g308, 256, 0, stream>>>(CAT, Wz1, zc1_b, Y, E_);      // gelu
    mixer_mfma<154, 160, 168, true, false><<<dim3(E_ / 64, B_), 256, 0, stream>>>(
        Y, Wz1p, zt1_b, nullptr, X2);
    gemm_bt<0><<<g154, 256, 0, stream>>>(X2, Wz2, zc2_b, X3, E_);
    mixer_mfma<77, 96, 104, false, true><<<dim3(E_ / 64, B_), 256, 0, stream>>>(
        X3, Wz2p, zt2_b, CAT, S);
    // output projection -> fp32 d_out
    gemm_bt<3><<<g154, 256, 0, stream>>>(S, Wo, o_b, (float*)d_out, E_);
}